// Round 2
// baseline (144.299 us; speedup 1.0000x reference)
//
#include <hip/hip_runtime.h>

#define NLAYER 255          // layers l = 1..255, layer_id k = l-1
#define SEQ    256          // cumsum length
#define TOTJ   32640        // sum_{l=1}^{255} (256-l)
#define CHUNKS 8
#define CHUNK_J (TOTJ / CHUNKS)   // 4080 (multiple of 4)
#define CHUNK_F4 (CHUNK_J / 4)    // 1020
#define THREADS 256

// ---------------------------------------------------------------------------
// Compile-time (layer_id | lo<<8) table, baked into the module as device
// .rodata. Loaded at module load time -> zero launches, zero workspace.
// ---------------------------------------------------------------------------
struct alignas(16) Table { unsigned short v[TOTJ]; };

constexpr Table make_table() {
    Table tb{};
    int j = 0;
    for (int l = 1; l <= 255; ++l)
        for (int i = 0; i < 256 - l; ++i)
            tb.v[j++] = (unsigned short)((l - 1) | (i << 8));
    return tb;
}
__device__ const Table TB = make_table();

// LDS swizzle for c[]: lanes gather at stride 4 (each thread owns a float4 of
// consecutive j). swz maps stride-4 index sequences onto consecutive banks.
__device__ __forceinline__ int swz(int i) {
    return (i >> 2) | ((i & 3) << 6);
}

// ---------------------------------------------------------------------------
// Single fused kernel. grid = (CHUNKS, B). Block handles one (row, j-chunk).
//  - wave-shuffle inclusive scan of d row -> c[256] swizzled (2 barriers)
//  - w[k] = mask^2.5 / (count_k * 255 * B) in LDS (full scale folded in)
//  - stream hvec chunk with float4, decode via compile-time table (ushort4)
//  - per-block partial -> atomicAdd(out)
// ---------------------------------------------------------------------------
__global__ __launch_bounds__(THREADS) void main_kernel(
        const float* __restrict__ d1layer,        // B x 255
        const float* __restrict__ hvec,           // B x 32640
        const float* __restrict__ mask,           // B x 255
        float* __restrict__ out,                  // scalar (pre-zeroed)
        float scale)                              // 1/(255*B)
{
    __shared__ float c[SEQ];          // swizzled cumsum
    __shared__ float w[NLAYER];
    __shared__ float wsum[THREADS / 64];
    __shared__ float red[THREADS / 64];

    const int b     = blockIdx.y;
    const int chunk = blockIdx.x;
    const int t     = threadIdx.x;
    const int lane  = t & 63, wid = t >> 6;

    // ---- stage fully-scaled w
    if (t < NLAYER) {
        float mk = mask[b * NLAYER + t];
        // mask^2.5 = mk*mk*sqrt(mk); fold /count_k, /255, /B (count = 255-k)
        w[t] = mk * mk * sqrtf(mk) * scale / (float)(NLAYER - t);
    }

    // ---- wave-shuffle inclusive scan: c[i] = sum d[0..i-1]
    float x = (t > 0) ? d1layer[b * NLAYER + (t - 1)] : 0.0f;
    #pragma unroll
    for (int off = 1; off < 64; off <<= 1) {
        float y = __shfl_up(x, off, 64);
        if (lane >= off) x += y;
    }
    if (lane == 63) wsum[wid] = x;
    __syncthreads();
    float prefix = 0.0f;
    #pragma unroll
    for (int i = 0; i < THREADS / 64; ++i)
        if (i < wid) prefix += wsum[i];
    c[swz(t)] = x + prefix;
    __syncthreads();

    // ---- stream hvec chunk
    const float4* hv4 =
        (const float4*)(hvec + (size_t)b * TOTJ + (size_t)chunk * CHUNK_J);
    const unsigned short* tb = TB.v + chunk * CHUNK_J;

    float acc = 0.0f;
    for (int f4 = t; f4 < CHUNK_F4; f4 += THREADS) {
        float4 h = hv4[f4];
        ushort4 tv = *(const ushort4*)(tb + f4 * 4);

        int k0 = tv.x & 0xFF, lo0 = tv.x >> 8;
        int k1 = tv.y & 0xFF, lo1 = tv.y >> 8;
        int k2 = tv.z & 0xFF, lo2 = tv.z >> 8;
        int k3 = tv.w & 0xFF, lo3 = tv.w >> 8;

        float d0 = (c[swz(lo0 + k0 + 1)] - c[swz(lo0)]) - h.x;
        float d1 = (c[swz(lo1 + k1 + 1)] - c[swz(lo1)]) - h.y;
        float d2 = (c[swz(lo2 + k2 + 1)] - c[swz(lo2)]) - h.z;
        float d3 = (c[swz(lo3 + k3 + 1)] - c[swz(lo3)]) - h.w;

        acc = fmaf(d0 * d0, w[k0], acc);
        acc = fmaf(d1 * d1, w[k1], acc);
        acc = fmaf(d2 * d2, w[k2], acc);
        acc = fmaf(d3 * d3, w[k3], acc);
    }

    // ---- wave (64-lane) shuffle reduce, then cross-wave via LDS
    #pragma unroll
    for (int off = 32; off > 0; off >>= 1)
        acc += __shfl_down(acc, off, 64);
    if (lane == 0) red[wid] = acc;
    __syncthreads();
    if (t == 0) {
        float s = 0.0f;
        #pragma unroll
        for (int i = 0; i < THREADS / 64; ++i) s += red[i];
        atomicAdd(out, s);   // device-scope float atomic, one per block
    }
}

// ---------------------------------------------------------------------------
extern "C" void kernel_launch(void* const* d_in, const int* in_sizes, int n_in,
                              void* d_out, int out_size, void* d_ws, size_t ws_size,
                              hipStream_t stream) {
    const float* d1layer = (const float*)d_in[0];   // B x 1 x 255
    const float* hvec    = (const float*)d_in[1];   // B x 32640
    const float* mask    = (const float*)d_in[2];   // B x 255
    float* out = (float*)d_out;

    const int B = in_sizes[2] / NLAYER;             // 512

    // zero the scalar accumulator (graph-capturable memset node)
    hipMemsetAsync(out, 0, sizeof(float), stream);

    const float scale = 1.0f / ((float)NLAYER * (float)B);
    dim3 grid(CHUNKS, B);
    main_kernel<<<grid, THREADS, 0, stream>>>(d1layer, hvec, mask, out, scale);
}

// Round 3
// 101.389 us; speedup vs baseline: 1.4232x; 1.4232x over previous
//
#include <hip/hip_runtime.h>

#define NLAYER 255          // layers l = 1..255, layer_id k = l-1
#define SEQ    256          // cumsum length
#define TOTJ   32640        // sum_{l=1}^{255} (256-l)
#define CHUNKS 4
#define CHUNK_J (TOTJ / CHUNKS)   // 8160 (multiple of 4)
#define CHUNK_F4 (CHUNK_J / 4)    // 2040
#define THREADS 256

// ---------------------------------------------------------------------------
// Compile-time (layer_id | lo<<8) table, baked into the module as device
// .rodata. Loaded at module load -> zero launches, zero table traffic setup.
// ---------------------------------------------------------------------------
struct alignas(16) Table { unsigned short v[TOTJ]; };

constexpr Table make_table() {
    Table tb{};
    int j = 0;
    for (int l = 1; l <= 255; ++l)
        for (int i = 0; i < 256 - l; ++i)
            tb.v[j++] = (unsigned short)((l - 1) | (i << 8));
    return tb;
}
__device__ const Table TB = make_table();

// LDS swizzle for c[]: lanes gather at stride 4 (each thread owns a float4 of
// consecutive j). swz maps stride-4 index sequences onto consecutive banks.
__device__ __forceinline__ int swz(int i) {
    return (i >> 2) | ((i & 3) << 6);
}

// ---------------------------------------------------------------------------
// Main kernel. grid = (CHUNKS, B) = 2048 blocks = exactly 8 blocks/CU.
//  - wave-shuffle inclusive scan of d row -> c[256] swizzled (2 barriers)
//  - w[k] = mask^2.5 / (count_k * 255 * B) in LDS (full scale folded in)
//  - stream hvec chunk with float4, decode via compile-time table (ushort4)
//  - ONE plain store per block into partials[] (NO same-address atomics:
//    4096 serialized atomicAdds were ~40 µs of round-1/2's 60 µs kernel)
// ---------------------------------------------------------------------------
__global__ __launch_bounds__(THREADS) void main_kernel(
        const float* __restrict__ d1layer,        // B x 255
        const float* __restrict__ hvec,           // B x 32640
        const float* __restrict__ mask,           // B x 255
        float* __restrict__ partials,             // CHUNKS*B  (in d_ws)
        float scale)                              // 1/(255*B)
{
    __shared__ float c[SEQ];          // swizzled cumsum
    __shared__ float w[NLAYER];
    __shared__ float wsum[THREADS / 64];
    __shared__ float red[THREADS / 64];

    const int b     = blockIdx.y;
    const int chunk = blockIdx.x;
    const int t     = threadIdx.x;
    const int lane  = t & 63, wid = t >> 6;

    // ---- stage fully-scaled w
    if (t < NLAYER) {
        float mk = mask[b * NLAYER + t];
        // mask^2.5 = mk*mk*sqrt(mk); fold /count_k, /255, /B (count = 255-k)
        w[t] = mk * mk * sqrtf(mk) * scale / (float)(NLAYER - t);
    }

    // ---- wave-shuffle inclusive scan: c[i] = sum d[0..i-1]
    float x = (t > 0) ? d1layer[b * NLAYER + (t - 1)] : 0.0f;
    #pragma unroll
    for (int off = 1; off < 64; off <<= 1) {
        float y = __shfl_up(x, off, 64);
        if (lane >= off) x += y;
    }
    if (lane == 63) wsum[wid] = x;
    __syncthreads();
    float prefix = 0.0f;
    #pragma unroll
    for (int i = 0; i < THREADS / 64; ++i)
        if (i < wid) prefix += wsum[i];
    c[swz(t)] = x + prefix;
    __syncthreads();

    // ---- stream hvec chunk (8 f4-iterations per thread)
    const float4* hv4 =
        (const float4*)(hvec + (size_t)b * TOTJ + (size_t)chunk * CHUNK_J);
    const unsigned short* tb = TB.v + chunk * CHUNK_J;

    float acc = 0.0f;
    #pragma unroll 2
    for (int f4 = t; f4 < CHUNK_F4; f4 += THREADS) {
        float4 h = hv4[f4];
        ushort4 tv = *(const ushort4*)(tb + f4 * 4);

        int k0 = tv.x & 0xFF, lo0 = tv.x >> 8;
        int k1 = tv.y & 0xFF, lo1 = tv.y >> 8;
        int k2 = tv.z & 0xFF, lo2 = tv.z >> 8;
        int k3 = tv.w & 0xFF, lo3 = tv.w >> 8;

        float d0 = (c[swz(lo0 + k0 + 1)] - c[swz(lo0)]) - h.x;
        float d1 = (c[swz(lo1 + k1 + 1)] - c[swz(lo1)]) - h.y;
        float d2 = (c[swz(lo2 + k2 + 1)] - c[swz(lo2)]) - h.z;
        float d3 = (c[swz(lo3 + k3 + 1)] - c[swz(lo3)]) - h.w;

        acc = fmaf(d0 * d0, w[k0], acc);
        acc = fmaf(d1 * d1, w[k1], acc);
        acc = fmaf(d2 * d2, w[k2], acc);
        acc = fmaf(d3 * d3, w[k3], acc);
    }

    // ---- wave (64-lane) shuffle reduce, then cross-wave via LDS
    #pragma unroll
    for (int off = 32; off > 0; off >>= 1)
        acc += __shfl_down(acc, off, 64);
    if (lane == 0) red[wid] = acc;
    __syncthreads();
    if (t == 0) {
        float s = 0.0f;
        #pragma unroll
        for (int i = 0; i < THREADS / 64; ++i) s += red[i];
        partials[b * CHUNKS + chunk] = s;   // plain store, distinct address
    }
}

// ---------------------------------------------------------------------------
// Reduce: one block sums CHUNKS*B partials (scale already folded into w).
// ---------------------------------------------------------------------------
__global__ __launch_bounds__(1024) void reduce_kernel(
        const float* __restrict__ partials, int n, float* __restrict__ out) {
    __shared__ float red[16];
    float acc = 0.0f;
    for (int i = threadIdx.x; i < n; i += 1024) acc += partials[i];
    #pragma unroll
    for (int off = 32; off > 0; off >>= 1)
        acc += __shfl_down(acc, off, 64);
    int lane = threadIdx.x & 63, wid = threadIdx.x >> 6;
    if (lane == 0) red[wid] = acc;
    __syncthreads();
    if (threadIdx.x == 0) {
        float s = 0.0f;
        #pragma unroll
        for (int i = 0; i < 16; ++i) s += red[i];
        out[0] = s;
    }
}

// ---------------------------------------------------------------------------
extern "C" void kernel_launch(void* const* d_in, const int* in_sizes, int n_in,
                              void* d_out, int out_size, void* d_ws, size_t ws_size,
                              hipStream_t stream) {
    const float* d1layer = (const float*)d_in[0];   // B x 1 x 255
    const float* hvec    = (const float*)d_in[1];   // B x 32640
    const float* mask    = (const float*)d_in[2];   // B x 255
    float* out = (float*)d_out;

    const int B = in_sizes[2] / NLAYER;             // 512
    float* partials = (float*)d_ws;                 // CHUNKS*B floats

    const float scale = 1.0f / ((float)NLAYER * (float)B);
    dim3 grid(CHUNKS, B);
    main_kernel<<<grid, THREADS, 0, stream>>>(d1layer, hvec, mask, partials, scale);
    reduce_kernel<<<1, 1024, 0, stream>>>(partials, CHUNKS * B, out);
}